// Round 1
// baseline (2458.244 us; speedup 1.0000x reference)
//
#include <hip/hip_runtime.h>

#define B_ 8192
#define D_ 1024
#define H_ 8192
#define K_ 64

// ---- monotonic fp32 <-> u32 key (descending top-k == largest keys) ----
__device__ __forceinline__ unsigned f2key(float f) {
  unsigned u = __float_as_uint(f);
  return (u & 0x80000000u) ? ~u : (u | 0x80000000u);
}
__device__ __forceinline__ float key2f(unsigned k) {
  return (k & 0x80000000u) ? __uint_as_float(k ^ 0x80000000u)
                           : __uint_as_float(~k);
}

// =====================================================================
// Encoder: z[b,h] = sum_d x[b,d]*We[h,d] + be[h]
// 128x128 tile, BK=16, 256 threads, 8x8 per-thread (4+4 split blocking)
// =====================================================================
__global__ __launch_bounds__(256) void encoder_kernel(
    const float* __restrict__ x, const float* __restrict__ We,
    const float* __restrict__ be, float* __restrict__ z)
{
  __shared__ float As[16][132];   // [k][m], padded
  __shared__ float Bs[16][132];   // [k][n], padded

  const int tid = threadIdx.x;
  const int bm = blockIdx.y * 128;
  const int bn = blockIdx.x * 128;
  const int tx = tid & 15;        // n block
  const int ty = tid >> 4;        // m block
  const int lr = tid >> 2;        // staging row 0..63
  const int lc = (tid & 3) << 2;  // staging col 0,4,8,12

  const float* pA0 = x  + (size_t)(bm + lr) * D_ + lc;
  const float* pA1 = x  + (size_t)(bm + lr + 64) * D_ + lc;
  const float* pB0 = We + (size_t)(bn + lr) * D_ + lc;
  const float* pB1 = We + (size_t)(bn + lr + 64) * D_ + lc;

  float acc[8][8];
#pragma unroll
  for (int i = 0; i < 8; ++i)
#pragma unroll
    for (int j = 0; j < 8; ++j) acc[i][j] = 0.f;

  // prefetch tile 0
  float4 a0 = *(const float4*)(pA0);
  float4 a1 = *(const float4*)(pA1);
  float4 b0 = *(const float4*)(pB0);
  float4 b1 = *(const float4*)(pB1);

  for (int k0 = 0; k0 < D_; k0 += 16) {
    __syncthreads();
    As[lc + 0][lr] = a0.x; As[lc + 1][lr] = a0.y; As[lc + 2][lr] = a0.z; As[lc + 3][lr] = a0.w;
    As[lc + 0][lr + 64] = a1.x; As[lc + 1][lr + 64] = a1.y; As[lc + 2][lr + 64] = a1.z; As[lc + 3][lr + 64] = a1.w;
    Bs[lc + 0][lr] = b0.x; Bs[lc + 1][lr] = b0.y; Bs[lc + 2][lr] = b0.z; Bs[lc + 3][lr] = b0.w;
    Bs[lc + 0][lr + 64] = b1.x; Bs[lc + 1][lr + 64] = b1.y; Bs[lc + 2][lr + 64] = b1.z; Bs[lc + 3][lr + 64] = b1.w;
    __syncthreads();

    if (k0 + 16 < D_) {   // software-pipelined prefetch of next K-tile
      a0 = *(const float4*)(pA0 + k0 + 16);
      a1 = *(const float4*)(pA1 + k0 + 16);
      b0 = *(const float4*)(pB0 + k0 + 16);
      b1 = *(const float4*)(pB1 + k0 + 16);
    }

#pragma unroll
    for (int k = 0; k < 16; ++k) {
      float a[8], b[8];
      *(float4*)&a[0] = *(const float4*)&As[k][ty * 4];
      *(float4*)&a[4] = *(const float4*)&As[k][64 + ty * 4];
      *(float4*)&b[0] = *(const float4*)&Bs[k][tx * 4];
      *(float4*)&b[4] = *(const float4*)&Bs[k][64 + tx * 4];
#pragma unroll
      for (int i = 0; i < 8; ++i)
#pragma unroll
        for (int j = 0; j < 8; ++j)
          acc[i][j] = fmaf(a[i], b[j], acc[i][j]);
    }
  }

  // epilogue: + be, store
  float bev[8];
#pragma unroll
  for (int j = 0; j < 8; ++j) {
    int cn = (j < 4) ? (bn + tx * 4 + j) : (bn + 64 + tx * 4 + (j - 4));
    bev[j] = be[cn];
  }
#pragma unroll
  for (int i = 0; i < 8; ++i) {
    int rm = (i < 4) ? (bm + ty * 4 + i) : (bm + 64 + ty * 4 + (i - 4));
    float4 v0 = make_float4(acc[i][0] + bev[0], acc[i][1] + bev[1],
                            acc[i][2] + bev[2], acc[i][3] + bev[3]);
    float4 v1 = make_float4(acc[i][4] + bev[4], acc[i][5] + bev[5],
                            acc[i][6] + bev[6], acc[i][7] + bev[7]);
    *(float4*)&z[(size_t)rm * H_ + bn + tx * 4] = v0;
    *(float4*)&z[(size_t)rm * H_ + bn + 64 + tx * 4] = v1;
  }
}

// =====================================================================
// Top-K per row, in place: reads z row from zsp, rewrites it as z_sparse.
// 4-pass radix select on monotonic u32 keys; lowest-index tie handling.
// =====================================================================
__global__ __launch_bounds__(256) void topk_kernel(float* __restrict__ zsp)
{
  __shared__ unsigned keys[H_];     // 32 KB
  __shared__ int hist[4][256];      // per-wave histograms
  __shared__ int suf[257];
  __shared__ unsigned s_prefix;
  __shared__ int s_need;
  __shared__ int s_eqcnt;
  __shared__ int eqbuf[1024];

  const int tid = threadIdx.x;
  const int wv = tid >> 6;
  float* __restrict__ zrow = zsp + (size_t)blockIdx.x * H_;

  // load row -> keys (coalesced float4)
#pragma unroll
  for (int t = 0; t < 8; ++t) {
    int i4 = tid + t * 256;
    float4 v = *(const float4*)&zrow[i4 * 4];
    keys[i4 * 4 + 0] = f2key(v.x);
    keys[i4 * 4 + 1] = f2key(v.y);
    keys[i4 * 4 + 2] = f2key(v.z);
    keys[i4 * 4 + 3] = f2key(v.w);
  }
  if (tid == 0) { s_prefix = 0u; s_need = K_; s_eqcnt = 0; }
  __syncthreads();

  for (int shift = 24; shift >= 0; shift -= 8) {
    hist[0][tid] = 0; hist[1][tid] = 0; hist[2][tid] = 0; hist[3][tid] = 0;
    __syncthreads();
    const unsigned pfx = s_prefix;
    const int need = s_need;
    const unsigned pmask = (shift == 24) ? 0u : (0xFFFFFFFFu << (shift + 8));
#pragma unroll 4
    for (int t = 0; t < 32; ++t) {
      unsigned key = keys[tid + t * 256];
      if ((key & pmask) == (pfx & pmask))
        atomicAdd(&hist[wv][(key >> shift) & 255], 1);
    }
    __syncthreads();
    int tot = hist[0][tid] + hist[1][tid] + hist[2][tid] + hist[3][tid];
    suf[tid] = tot;
    if (tid == 0) suf[256] = 0;
    __syncthreads();
    // inclusive suffix sum over 256 bins
    for (int off = 1; off < 256; off <<= 1) {
      int v = suf[tid] + ((tid + off < 256) ? suf[tid + off] : 0);
      __syncthreads();
      suf[tid] = v;
      __syncthreads();
    }
    if (suf[tid] >= need && suf[tid + 1] < need) {   // exactly one thread
      s_prefix = pfx | ((unsigned)tid << shift);
      s_need = need - suf[tid + 1];
    }
    __syncthreads();
  }

  const unsigned thr = s_prefix;   // exact key of Kth largest
  const int needEq = s_need;       // how many ==thr to take (lowest indices)

  // rewrite row: keep key>thr, zero others, collect ==thr candidates
#pragma unroll
  for (int t = 0; t < 8; ++t) {
    int base = (tid + t * 256) * 4;
    float ov[4];
#pragma unroll
    for (int j = 0; j < 4; ++j) {
      unsigned key = keys[base + j];
      float v = 0.f;
      if (key > thr) v = key2f(key);
      else if (key == thr) {
        int p = atomicAdd(&s_eqcnt, 1);
        if (p < 1024) eqbuf[p] = base + j;
      }
      ov[j] = v;
    }
    *(float4*)&zrow[base] = make_float4(ov[0], ov[1], ov[2], ov[3]);
  }
  __syncthreads();
  int ec = min(s_eqcnt, 1024);
  for (int p = tid; p < ec; p += 256) {
    int myi = eqbuf[p];
    int rank = 0;
    for (int q = 0; q < ec; ++q) rank += (eqbuf[q] < myi);
    if (rank < needEq) zrow[myi] = key2f(thr);
  }
}

// =====================================================================
// Decoder: recon[b,:] = bd + sum_k v_k * We[h_k,:]   (Wd == We.T)
// one block per row; gathers nonzeros from z_sparse row.
// =====================================================================
__global__ __launch_bounds__(256) void decoder_kernel(
    const float* __restrict__ zsp, const float* __restrict__ We,
    const float* __restrict__ bd, float* __restrict__ recon)
{
  __shared__ float svals[K_];
  __shared__ int sidx[K_];
  __shared__ int s_cnt;
  const int tid = threadIdx.x;
  const float* zrow = zsp + (size_t)blockIdx.x * H_;
  if (tid == 0) s_cnt = 0;
  __syncthreads();
#pragma unroll
  for (int t = 0; t < 8; ++t) {
    int base = (tid + t * 256) * 4;
    float4 v = *(const float4*)&zrow[base];
    float vv[4] = {v.x, v.y, v.z, v.w};
#pragma unroll
    for (int j = 0; j < 4; ++j) {
      if (vv[j] != 0.f) {
        int p = atomicAdd(&s_cnt, 1);
        if (p < K_) { svals[p] = vv[j]; sidx[p] = base + j; }
      }
    }
  }
  __syncthreads();
  const int n = min(s_cnt, K_);
  const int d0 = tid * 4;
  float4 a = *(const float4*)&bd[d0];
  for (int k = 0; k < n; ++k) {
    const float v = svals[k];
    const float4 w = *(const float4*)&We[(size_t)sidx[k] * D_ + d0];
    a.x = fmaf(v, w.x, a.x);
    a.y = fmaf(v, w.y, a.y);
    a.z = fmaf(v, w.z, a.z);
    a.w = fmaf(v, w.w, a.w);
  }
  *(float4*)&recon[(size_t)blockIdx.x * D_ + d0] = a;
}

extern "C" void kernel_launch(void* const* d_in, const int* in_sizes, int n_in,
                              void* d_out, int out_size, void* d_ws, size_t ws_size,
                              hipStream_t stream) {
  const float* x  = (const float*)d_in[0];
  const float* We = (const float*)d_in[1];
  const float* be = (const float*)d_in[2];
  // d_in[3] is Wd == We.T; we gather rows of We instead (contiguous).
  const float* bd = (const float*)d_in[4];

  float* recon = (float*)d_out;                       // (B, D)
  float* zsp   = (float*)d_out + (size_t)B_ * D_;     // (B, H): z, then z_sparse in place

  encoder_kernel<<<dim3(H_ / 128, B_ / 128), 256, 0, stream>>>(x, We, be, zsp);
  topk_kernel<<<dim3(B_), 256, 0, stream>>>(zsp);
  decoder_kernel<<<dim3(B_), 256, 0, stream>>>(zsp, We, bd, recon);
}

// Round 5
// 1452.251 us; speedup vs baseline: 1.6927x; 1.6927x over previous
//
#include <hip/hip_runtime.h>

#define B_ 8192
#define D_ 1024
#define H_ 8192
#define K_ 64
#define KPHYS 2048   // [hi | lo] bf16 columns
#define DELTA 8e-3f  // boundary band half-width (~800x any z~ / fp32 error)

typedef __attribute__((ext_vector_type(8))) short bf16x8;
typedef __attribute__((ext_vector_type(4))) float f32x4;

// ---- monotonic fp32 <-> u32 key (descending top-k == largest keys) ----
__device__ __forceinline__ unsigned f2key(float f) {
  unsigned u = __float_as_uint(f);
  return (u & 0x80000000u) ? ~u : (u | 0x80000000u);
}
__device__ __forceinline__ float key2f(unsigned k) {
  return (k & 0x80000000u) ? __uint_as_float(k ^ 0x80000000u)
                           : __uint_as_float(~k);
}

__device__ __forceinline__ unsigned short f32_to_bf16_rne(float f) {
  unsigned u = __float_as_uint(f);
  unsigned r = (u + 0x7FFFu + ((u >> 16) & 1u)) >> 16;
  return (unsigned short)r;
}
__device__ __forceinline__ float bf16_to_f32(unsigned short h) {
  return __uint_as_float(((unsigned)h) << 16);
}

__device__ __forceinline__ void gload_lds16(const void* g, void* l) {
  __builtin_amdgcn_global_load_lds(
      (const __attribute__((address_space(1))) unsigned int*)g,
      (__attribute__((address_space(3))) unsigned int*)l, 16, 0, 0);
}

// =====================================================================
// Split fp32 (R x 1024) -> bf16 [hi | lo] (R x 2048)
// =====================================================================
__global__ __launch_bounds__(256) void split_bf16_kernel(
    const float* __restrict__ src, unsigned short* __restrict__ dst)
{
  const int i = blockIdx.x * 256 + threadIdx.x;   // float4 index
  const int row = i >> 8;                          // 256 float4 per row
  const int c4 = (i & 255) << 2;
  float4 v = *(const float4*)&src[(size_t)row * D_ + c4];
  float f[4] = {v.x, v.y, v.z, v.w};
  ushort4 hi, lo;
  unsigned short* hp = (unsigned short*)&hi;
  unsigned short* lp = (unsigned short*)&lo;
#pragma unroll
  for (int j = 0; j < 4; ++j) {
    unsigned short h = f32_to_bf16_rne(f[j]);
    hp[j] = h;
    lp[j] = f32_to_bf16_rne(f[j] - bf16_to_f32(h));
  }
  unsigned short* drow = dst + (size_t)row * KPHYS;
  *(ushort4*)&drow[c4] = hi;
  *(ushort4*)&drow[1024 + c4] = lo;
}

// =====================================================================
// Encoder GEMM: z[m][n] = sum_k x[m][k]*We[n][k] + be[n]
// 3-term split-bf16: (hi,hi)+(hi,lo)+(lo,hi). 128x128 tile, BK=64,
// 4 waves (2x2), 16x16x32 bf16 MFMA, global_load_lds width=16.
// =====================================================================
__global__ __launch_bounds__(256) void enc_mfma_kernel(
    const unsigned short* __restrict__ Ac,  // (B_, 2048)
    const unsigned short* __restrict__ Bc,  // (H_, 2048)
    const float* __restrict__ be, float* __restrict__ z)
{
  __shared__ unsigned short As[128 * 64];  // row-major [m][k]
  __shared__ unsigned short Bs[128 * 64];  // row-major [n][k]

  const int tid = threadIdx.x;
  const int lane = tid & 63;
  const int wave = tid >> 6;
  const int wm = wave >> 1, wn = wave & 1;
  const int bm = blockIdx.y * 128;
  const int bn = blockIdx.x * 128;

  const int srow = lane >> 3;        // 0..7
  const int scol = (lane & 7) * 8;   // bf16 col 0..56
  const unsigned short* pA[4];
  const unsigned short* pB[4];
  unsigned short* lA[4];
  unsigned short* lB[4];
#pragma unroll
  for (int it = 0; it < 4; ++it) {
    const int row = wave * 32 + it * 8 + srow;
    pA[it] = Ac + (size_t)(bm + row) * KPHYS + scol;
    pB[it] = Bc + (size_t)(bn + row) * KPHYS + scol;
    lA[it] = &As[(wave * 4 + it) * 512];
    lB[it] = &Bs[(wave * 4 + it) * 512];
  }

  f32x4 acc[4][4];
#pragma unroll
  for (int mi = 0; mi < 4; ++mi)
#pragma unroll
    for (int ni = 0; ni < 4; ++ni) acc[mi][ni] = (f32x4){0.f, 0.f, 0.f, 0.f};

  const int mrow = wm * 64 + (lane & 15);
  const int nrow = wn * 64 + (lane & 15);
  const int kgrp = (lane >> 4) * 8;

  for (int s = 0; s < 48; ++s) {
    const int seg = s >> 4, t = s & 15;
    const int kA = ((seg == 2) ? 1024 : 0) + t * 64;
    const int kB = ((seg == 1) ? 1024 : 0) + t * 64;
#pragma unroll
    for (int it = 0; it < 4; ++it) gload_lds16(pA[it] + kA, lA[it]);
#pragma unroll
    for (int it = 0; it < 4; ++it) gload_lds16(pB[it] + kB, lB[it]);
    __syncthreads();

#pragma unroll
    for (int kk = 0; kk < 2; ++kk) {
      const int ko = kk * 32 + kgrp;
      bf16x8 af[4], bfr[4];
#pragma unroll
      for (int mi = 0; mi < 4; ++mi)
        af[mi] = *(const bf16x8*)&As[(mrow + mi * 16) * 64 + ko];
#pragma unroll
      for (int ni = 0; ni < 4; ++ni)
        bfr[ni] = *(const bf16x8*)&Bs[(nrow + ni * 16) * 64 + ko];
#pragma unroll
      for (int mi = 0; mi < 4; ++mi)
#pragma unroll
        for (int ni = 0; ni < 4; ++ni)
          acc[mi][ni] = __builtin_amdgcn_mfma_f32_16x16x32_bf16(
              af[mi], bfr[ni], acc[mi][ni], 0, 0, 0);
    }
    __syncthreads();
  }

  float bev[4];
#pragma unroll
  for (int ni = 0; ni < 4; ++ni) bev[ni] = be[bn + wn * 64 + ni * 16 + (lane & 15)];
#pragma unroll
  for (int mi = 0; mi < 4; ++mi) {
#pragma unroll
    for (int r = 0; r < 4; ++r) {
      const int row = bm + wm * 64 + mi * 16 + (lane >> 4) * 4 + r;
      float* zr = &z[(size_t)row * H_ + bn + wn * 64 + (lane & 15)];
#pragma unroll
      for (int ni = 0; ni < 4; ++ni) zr[ni * 16] = acc[mi][ni][r] + bev[ni];
    }
  }
}

// =====================================================================
// Fused Top-K + round-1-arithmetic boundary fixup + decode.
// 1) radix-select approx 64th value thr~ from z~ row
// 2) safe-select z~ > thr~+DELTA; candidates |z~-thr~|<=DELTA
// 3) recompute candidates' z with EXACTLY round-1's arithmetic:
//    sequential ascending-k fp32 fmaf chain, then +be (separate add).
//    (Accurate fp64 reordering FAILED vs the fp32-computed np ref —
//    rounds 3/4; matching the empirically-passing fp32 order is the fix.)
// 4) pick remaining (64-S) among candidates by that value, idx tie-break
// 5) write z_sparse row; recon[b,:] = bd + sum v_k * We[h_k,:]
// =====================================================================
__global__ __launch_bounds__(256) void topk_decode_kernel(
    float* __restrict__ zsp, const float* __restrict__ x,
    const float* __restrict__ We, const float* __restrict__ be,
    const float* __restrict__ bd, float* __restrict__ recon)
{
  __shared__ unsigned keys[H_];     // 32 KB
  __shared__ float xsh[D_];         // 4 KB: x row for candidate recompute
  __shared__ int hist[4][256];
  __shared__ int suf[257];
  __shared__ unsigned s_prefix;
  __shared__ int s_need;
  __shared__ int s_cnt;            // entries in svals/sidx
  __shared__ int s_nc;             // candidate count
  __shared__ int cand[128];
  __shared__ float zex[128];
  __shared__ float svals[96];
  __shared__ int sidx[96];

  const int tid = threadIdx.x;
  const int wv = tid >> 6;
  const int bid = blockIdx.x;
  float* __restrict__ zrow = zsp + (size_t)bid * H_;

#pragma unroll
  for (int t = 0; t < 8; ++t) {
    int i4 = tid + t * 256;
    float4 v = *(const float4*)&zrow[i4 * 4];
    keys[i4 * 4 + 0] = f2key(v.x);
    keys[i4 * 4 + 1] = f2key(v.y);
    keys[i4 * 4 + 2] = f2key(v.z);
    keys[i4 * 4 + 3] = f2key(v.w);
  }
  if (tid == 0) { s_prefix = 0u; s_need = K_; s_cnt = 0; s_nc = 0; }
  __syncthreads();

  // ---- 4-pass radix select of the 64th-largest key ----
  for (int shift = 24; shift >= 0; shift -= 8) {
    hist[0][tid] = 0; hist[1][tid] = 0; hist[2][tid] = 0; hist[3][tid] = 0;
    __syncthreads();
    const unsigned pfx = s_prefix;
    const int need = s_need;
    const unsigned pmask = (shift == 24) ? 0u : (0xFFFFFFFFu << (shift + 8));
#pragma unroll 4
    for (int t = 0; t < 32; ++t) {
      unsigned key = keys[tid + t * 256];
      if ((key & pmask) == (pfx & pmask))
        atomicAdd(&hist[wv][(key >> shift) & 255], 1);
    }
    __syncthreads();
    int tot = hist[0][tid] + hist[1][tid] + hist[2][tid] + hist[3][tid];
    suf[tid] = tot;
    if (tid == 0) suf[256] = 0;
    __syncthreads();
    for (int off = 1; off < 256; off <<= 1) {
      int v = suf[tid] + ((tid + off < 256) ? suf[tid + off] : 0);
      __syncthreads();
      suf[tid] = v;
      __syncthreads();
    }
    if (suf[tid] >= need && suf[tid + 1] < need) {
      s_prefix = pfx | ((unsigned)tid << shift);
      s_need = need - suf[tid + 1];
    }
    __syncthreads();
  }

  const float vthr = key2f(s_prefix);
  const unsigned hiKey = f2key(vthr + DELTA);
  const unsigned loKey = f2key(vthr - DELTA);

  // ---- classify + write zeros/safe values, collect candidates ----
#pragma unroll
  for (int t = 0; t < 8; ++t) {
    int base = (tid + t * 256) * 4;
    float ov[4];
#pragma unroll
    for (int j = 0; j < 4; ++j) {
      unsigned key = keys[base + j];
      float v = 0.f;
      if (key > hiKey) {                 // safely in top-64
        v = key2f(key);
        int p = atomicAdd(&s_cnt, 1);
        if (p < 96) { svals[p] = v; sidx[p] = base + j; }
      } else if (key >= loKey) {         // boundary candidate
        int p = atomicAdd(&s_nc, 1);
        if (p < 128) cand[p] = base + j;
      }
      ov[j] = v;
    }
    *(float4*)&zrow[base] = make_float4(ov[0], ov[1], ov[2], ov[3]);
  }
  // stage x row for candidate recompute
  for (int i = tid; i < D_; i += 256) xsh[i] = x[(size_t)bid * D_ + i];
  __syncthreads();

  const int S = min(s_cnt, 96);
  const int nc = min(s_nc, 128);
  const int needC = K_ - S;

  // ---- round-1-arithmetic recompute of candidates (one thread each) ----
  if (tid < nc) {
    const int h = cand[tid];
    const float* __restrict__ wrow = &We[(size_t)h * D_];
    float acc = 0.f;
    for (int k = 0; k < D_; ++k) acc = fmaf(xsh[k], wrow[k], acc);
    zex[tid] = acc + be[h];
  }
  __syncthreads();

  // ---- select needC among candidates (idx tie-break) ----
  for (int c = tid; c < nc; c += 256) {
    const float zc = zex[c];
    const int hc = cand[c];
    int rank = 0;
    for (int q = 0; q < nc; ++q) {
      float zq = zex[q];
      rank += (zq > zc) || (zq == zc && cand[q] < hc);
    }
    if (rank < needC) {
      zrow[hc] = zc;
      int p = atomicAdd(&s_cnt, 1);
      if (p < 96) { svals[p] = zc; sidx[p] = hc; }
    }
  }
  __syncthreads();

  // ---- decode ----
  const int n = min(s_cnt, 96);
  const int d0 = tid * 4;
  float4 a = *(const float4*)&bd[d0];
  for (int k = 0; k < n; ++k) {
    const float v = svals[k];
    const float4 w = *(const float4*)&We[(size_t)sidx[k] * D_ + d0];
    a.x = fmaf(v, w.x, a.x);
    a.y = fmaf(v, w.y, a.y);
    a.z = fmaf(v, w.z, a.z);
    a.w = fmaf(v, w.w, a.w);
  }
  *(float4*)&recon[(size_t)bid * D_ + d0] = a;
}

// =====================================================================
// Fallback fp32 encoder (only if ws too small) — round-1 validated.
// =====================================================================
__global__ __launch_bounds__(256) void encoder_kernel(
    const float* __restrict__ x, const float* __restrict__ We,
    const float* __restrict__ be, float* __restrict__ z)
{
  __shared__ float Asf[16][132];
  __shared__ float Bsf[16][132];
  const int tid = threadIdx.x;
  const int bm = blockIdx.y * 128;
  const int bn = blockIdx.x * 128;
  const int tx = tid & 15;
  const int ty = tid >> 4;
  const int lr = tid >> 2;
  const int lc = (tid & 3) << 2;
  const float* pA0 = x + (size_t)(bm + lr) * D_ + lc;
  const float* pA1 = x + (size_t)(bm + lr + 64) * D_ + lc;
  const float* pB0 = We + (size_t)(bn + lr) * D_ + lc;
  const float* pB1 = We + (size_t)(bn + lr + 64) * D_ + lc;
  float acc[8][8];
#pragma unroll
  for (int i = 0; i < 8; ++i)
#pragma unroll
    for (int j = 0; j < 8; ++j) acc[i][j] = 0.f;
  float4 a0 = *(const float4*)(pA0);
  float4 a1 = *(const float4*)(pA1);
  float4 b0 = *(const float4*)(pB0);
  float4 b1 = *(const float4*)(pB1);
  for (int k0 = 0; k0 < D_; k0 += 16) {
    __syncthreads();
    Asf[lc + 0][lr] = a0.x; Asf[lc + 1][lr] = a0.y; Asf[lc + 2][lr] = a0.z; Asf[lc + 3][lr] = a0.w;
    Asf[lc + 0][lr + 64] = a1.x; Asf[lc + 1][lr + 64] = a1.y; Asf[lc + 2][lr + 64] = a1.z; Asf[lc + 3][lr + 64] = a1.w;
    Bsf[lc + 0][lr] = b0.x; Bsf[lc + 1][lr] = b0.y; Bsf[lc + 2][lr] = b0.z; Bsf[lc + 3][lr] = b0.w;
    Bsf[lc + 0][lr + 64] = b1.x; Bsf[lc + 1][lr + 64] = b1.y; Bsf[lc + 2][lr + 64] = b1.z; Bsf[lc + 3][lr + 64] = b1.w;
    __syncthreads();
    if (k0 + 16 < D_) {
      a0 = *(const float4*)(pA0 + k0 + 16);
      a1 = *(const float4*)(pA1 + k0 + 16);
      b0 = *(const float4*)(pB0 + k0 + 16);
      b1 = *(const float4*)(pB1 + k0 + 16);
    }
#pragma unroll
    for (int k = 0; k < 16; ++k) {
      float a[8], b[8];
      *(float4*)&a[0] = *(const float4*)&Asf[k][ty * 4];
      *(float4*)&a[4] = *(const float4*)&Asf[k][64 + ty * 4];
      *(float4*)&b[0] = *(const float4*)&Bsf[k][tx * 4];
      *(float4*)&b[4] = *(const float4*)&Bsf[k][64 + tx * 4];
#pragma unroll
      for (int i = 0; i < 8; ++i)
#pragma unroll
        for (int j = 0; j < 8; ++j) acc[i][j] = fmaf(a[i], b[j], acc[i][j]);
    }
  }
  float bev[8];
#pragma unroll
  for (int j = 0; j < 8; ++j) {
    int cn = (j < 4) ? (bn + tx * 4 + j) : (bn + 64 + tx * 4 + (j - 4));
    bev[j] = be[cn];
  }
#pragma unroll
  for (int i = 0; i < 8; ++i) {
    int rm = (i < 4) ? (bm + ty * 4 + i) : (bm + 64 + ty * 4 + (i - 4));
    float4 v0 = make_float4(acc[i][0] + bev[0], acc[i][1] + bev[1],
                            acc[i][2] + bev[2], acc[i][3] + bev[3]);
    float4 v1 = make_float4(acc[i][4] + bev[4], acc[i][5] + bev[5],
                            acc[i][6] + bev[6], acc[i][7] + bev[7]);
    *(float4*)&z[(size_t)rm * H_ + bn + tx * 4] = v0;
    *(float4*)&z[(size_t)rm * H_ + bn + 64 + tx * 4] = v1;
  }
}

extern "C" void kernel_launch(void* const* d_in, const int* in_sizes, int n_in,
                              void* d_out, int out_size, void* d_ws, size_t ws_size,
                              hipStream_t stream) {
  const float* x  = (const float*)d_in[0];
  const float* We = (const float*)d_in[1];
  const float* be = (const float*)d_in[2];
  const float* bd = (const float*)d_in[4];   // d_in[3]=Wd==We.T unused; gather We rows

  float* recon = (float*)d_out;                     // (B, D)
  float* zsp   = (float*)d_out + (size_t)B_ * D_;   // (B, H): z -> z_sparse in place

  const size_t need_ws = 2ull * 8192 * KPHYS * sizeof(unsigned short);  // 67.1 MB
  if (ws_size >= need_ws) {
    unsigned short* Ac = (unsigned short*)d_ws;
    unsigned short* Bc = Ac + (size_t)8192 * KPHYS;
    split_bf16_kernel<<<8192, 256, 0, stream>>>(x, Ac);
    split_bf16_kernel<<<8192, 256, 0, stream>>>(We, Bc);
    enc_mfma_kernel<<<dim3(64, 64), 256, 0, stream>>>(Ac, Bc, be, zsp);
  } else {
    encoder_kernel<<<dim3(64, 64), 256, 0, stream>>>(x, We, be, zsp);
  }
  topk_decode_kernel<<<B_, 256, 0, stream>>>(zsp, x, We, be, bd, recon);
}

// Round 6
// 1264.256 us; speedup vs baseline: 1.9444x; 1.1487x over previous
//
#include <hip/hip_runtime.h>

#define B_ 8192
#define D_ 1024
#define H_ 8192
#define K_ 64
#define KPHYS 2048   // [hi | lo] bf16 columns
#define DELTA 8e-3f  // boundary band half-width (~800x any z~ / fp32 error)

typedef __attribute__((ext_vector_type(8))) short bf16x8;
typedef __attribute__((ext_vector_type(4))) float f32x4;

// ---- monotonic fp32 <-> u32 key (descending top-k == largest keys) ----
__device__ __forceinline__ unsigned f2key(float f) {
  unsigned u = __float_as_uint(f);
  return (u & 0x80000000u) ? ~u : (u | 0x80000000u);
}
__device__ __forceinline__ float key2f(unsigned k) {
  return (k & 0x80000000u) ? __uint_as_float(k ^ 0x80000000u)
                           : __uint_as_float(~k);
}

__device__ __forceinline__ unsigned short f32_to_bf16_rne(float f) {
  unsigned u = __float_as_uint(f);
  unsigned r = (u + 0x7FFFu + ((u >> 16) & 1u)) >> 16;
  return (unsigned short)r;
}
__device__ __forceinline__ float bf16_to_f32(unsigned short h) {
  return __uint_as_float(((unsigned)h) << 16);
}

__device__ __forceinline__ void gload_lds16(const void* g, void* l) {
  __builtin_amdgcn_global_load_lds(
      (const __attribute__((address_space(1))) unsigned int*)g,
      (__attribute__((address_space(3))) unsigned int*)l, 16, 0, 0);
}

// =====================================================================
// Split fp32 (R x 1024) -> bf16 [hi | lo] (R x 2048)
// =====================================================================
__global__ __launch_bounds__(256) void split_bf16_kernel(
    const float* __restrict__ src, unsigned short* __restrict__ dst)
{
  const int i = blockIdx.x * 256 + threadIdx.x;   // float4 index
  const int row = i >> 8;                          // 256 float4 per row
  const int c4 = (i & 255) << 2;
  float4 v = *(const float4*)&src[(size_t)row * D_ + c4];
  float f[4] = {v.x, v.y, v.z, v.w};
  ushort4 hi, lo;
  unsigned short* hp = (unsigned short*)&hi;
  unsigned short* lp = (unsigned short*)&lo;
#pragma unroll
  for (int j = 0; j < 4; ++j) {
    unsigned short h = f32_to_bf16_rne(f[j]);
    hp[j] = h;
    lp[j] = f32_to_bf16_rne(f[j] - bf16_to_f32(h));
  }
  unsigned short* drow = dst + (size_t)row * KPHYS;
  *(ushort4*)&drow[c4] = hi;
  *(ushort4*)&drow[1024 + c4] = lo;
}

// =====================================================================
// Encoder GEMM: z[m][n] = sum_k x[m][k]*We[n][k] + be[n]
// 3-term split-bf16. 128x128 tile, BK=64, 4 waves, 16x16x32 bf16 MFMA.
// Bank-conflict fix (rule #21 both-sides): LDS stays LINEAR for
// global_load_lds; the per-lane GLOBAL source col is pre-swizzled by the
// involution cb ^= ((row&7)<<4) (within each 128B row), and fragment
// reads apply the same XOR. 16-way -> 2-way (free).
// =====================================================================
__global__ __launch_bounds__(256) void enc_mfma_kernel(
    const unsigned short* __restrict__ Ac,  // (B_, 2048)
    const unsigned short* __restrict__ Bc,  // (H_, 2048)
    const float* __restrict__ be, float* __restrict__ z)
{
  __shared__ unsigned short As[128 * 64];  // [row][64], row-major, linear
  __shared__ unsigned short Bs[128 * 64];

  const int tid = threadIdx.x;
  const int lane = tid & 63;
  const int wave = tid >> 6;
  const int wm = wave >> 1, wn = wave & 1;
  const int bm = blockIdx.y * 128;
  const int bn = blockIdx.x * 128;

  const int srow = lane >> 3;                            // 0..7 within chunk
  const int scol = (((lane & 7) ^ (lane >> 3)) << 3);    // SWIZZLED src col (elems)
  const unsigned short* pA[4];
  const unsigned short* pB[4];
  unsigned short* lA[4];
  unsigned short* lB[4];
#pragma unroll
  for (int it = 0; it < 4; ++it) {
    const int row = wave * 32 + it * 8 + srow;
    pA[it] = Ac + (size_t)(bm + row) * KPHYS + scol;
    pB[it] = Bc + (size_t)(bn + row) * KPHYS + scol;
    lA[it] = &As[(wave * 4 + it) * 512];
    lB[it] = &Bs[(wave * 4 + it) * 512];
  }

  f32x4 acc[4][4];
#pragma unroll
  for (int mi = 0; mi < 4; ++mi)
#pragma unroll
    for (int ni = 0; ni < 4; ++ni) acc[mi][ni] = (f32x4){0.f, 0.f, 0.f, 0.f};

  const int mrow = wm * 64 + (lane & 15);
  const int nrow = wn * 64 + (lane & 15);
  const int rsw = (lane & 7) << 4;          // read-side XOR field (bytes)
  const int cgrp = (lane >> 4) << 4;        // col-group byte offset within 64B half

  for (int s = 0; s < 48; ++s) {
    const int seg = s >> 4, t = s & 15;
    const int kA = ((seg == 2) ? 1024 : 0) + t * 64;
    const int kB = ((seg == 1) ? 1024 : 0) + t * 64;
#pragma unroll
    for (int it = 0; it < 4; ++it) gload_lds16(pA[it] + kA, lA[it]);
#pragma unroll
    for (int it = 0; it < 4; ++it) gload_lds16(pB[it] + kB, lB[it]);
    __syncthreads();

#pragma unroll
    for (int kk = 0; kk < 2; ++kk) {
      const int ko = ((kk * 64 + cgrp) ^ rsw) >> 1;   // swizzled elem offset
      bf16x8 af[4], bfr[4];
#pragma unroll
      for (int mi = 0; mi < 4; ++mi)
        af[mi] = *(const bf16x8*)&As[(mrow + mi * 16) * 64 + ko];
#pragma unroll
      for (int ni = 0; ni < 4; ++ni)
        bfr[ni] = *(const bf16x8*)&Bs[(nrow + ni * 16) * 64 + ko];
#pragma unroll
      for (int mi = 0; mi < 4; ++mi)
#pragma unroll
        for (int ni = 0; ni < 4; ++ni)
          acc[mi][ni] = __builtin_amdgcn_mfma_f32_16x16x32_bf16(
              af[mi], bfr[ni], acc[mi][ni], 0, 0, 0);
    }
    __syncthreads();
  }

  float bev[4];
#pragma unroll
  for (int ni = 0; ni < 4; ++ni) bev[ni] = be[bn + wn * 64 + ni * 16 + (lane & 15)];
#pragma unroll
  for (int mi = 0; mi < 4; ++mi) {
#pragma unroll
    for (int r = 0; r < 4; ++r) {
      const int row = bm + wm * 64 + mi * 16 + (lane >> 4) * 4 + r;
      float* zr = &z[(size_t)row * H_ + bn + wn * 64 + (lane & 15)];
#pragma unroll
      for (int ni = 0; ni < 4; ++ni) zr[ni * 16] = acc[mi][ni][r] + bev[ni];
    }
  }
}

// =====================================================================
// Fused Top-K + round-1-arithmetic boundary fixup + decode.
// Keys live in REGISTERS (32/thread). 64th value found by 32-iter
// bisection on u32 key space: 32 cmp-adds + shfl-reduce + ONE barrier
// per iter (parity-buffered cross-wave sum). No LDS atomics, no 32KB
// keys array -> ~6KB LDS, 8 blocks/CU resident.
// =====================================================================
__global__ __launch_bounds__(256) void topk_decode_kernel(
    float* __restrict__ zsp, const float* __restrict__ x,
    const float* __restrict__ We, const float* __restrict__ be,
    const float* __restrict__ bd, float* __restrict__ recon)
{
  __shared__ float xsh[D_];         // 4 KB: x row for candidate recompute
  __shared__ int scnt[2][4];        // parity-buffered wave sums
  __shared__ int s_cnt;             // entries in svals/sidx
  __shared__ int s_nc;              // candidate count
  __shared__ int cand[128];
  __shared__ float zex[128];
  __shared__ float svals[96];
  __shared__ int sidx[96];

  const int tid = threadIdx.x;
  const int wv = tid >> 6;
  const int bid = blockIdx.x;
  float* __restrict__ zrow = zsp + (size_t)bid * H_;

  // load 32 keys/thread into registers (coalesced float4)
  unsigned k[32];
#pragma unroll
  for (int t = 0; t < 8; ++t) {
    const int i4 = tid + t * 256;
    float4 v = *(const float4*)&zrow[i4 * 4];
    k[t * 4 + 0] = f2key(v.x);
    k[t * 4 + 1] = f2key(v.y);
    k[t * 4 + 2] = f2key(v.z);
    k[t * 4 + 3] = f2key(v.w);
  }
  // stage x row
  for (int i = tid; i < D_; i += 256) xsh[i] = x[(size_t)bid * D_ + i];
  if (tid == 0) { s_cnt = 0; s_nc = 0; }

  // ---- bisection for the exact 64th-largest key ----
  // invariant: cnt(>=lo) >= K, cnt(>=hi) < K
  unsigned lo = 0u, hi = 0xFFFFFFFFu;
  int par = 0;
  while (hi - lo > 1u) {
    const unsigned mid = lo + ((hi - lo) >> 1);
    int c = 0;
#pragma unroll
    for (int t = 0; t < 32; ++t) c += (k[t] >= mid) ? 1 : 0;
#pragma unroll
    for (int off = 32; off > 0; off >>= 1) c += __shfl_down(c, off);
    if ((tid & 63) == 0) scnt[par][wv] = c;
    __syncthreads();
    const int tot = scnt[par][0] + scnt[par][1] + scnt[par][2] + scnt[par][3];
    if (tot >= K_) lo = mid; else hi = mid;
    par ^= 1;
  }

  const float vthr = key2f(lo);     // exact 64th-largest approx-z value
  const unsigned hiKey = f2key(vthr + DELTA);
  const unsigned loKey = f2key(vthr - DELTA);

  // ---- classify + write zeros/safe values, collect candidates ----
#pragma unroll
  for (int t = 0; t < 8; ++t) {
    const int base = (tid + t * 256) * 4;
    float ov[4];
#pragma unroll
    for (int j = 0; j < 4; ++j) {
      const unsigned key = k[t * 4 + j];
      float v = 0.f;
      if (key > hiKey) {                 // safely in top-64
        v = key2f(key);
        int p = atomicAdd(&s_cnt, 1);
        if (p < 96) { svals[p] = v; sidx[p] = base + j; }
      } else if (key >= loKey) {         // boundary candidate
        int p = atomicAdd(&s_nc, 1);
        if (p < 128) cand[p] = base + j;
      }
      ov[j] = v;
    }
    *(float4*)&zrow[base] = make_float4(ov[0], ov[1], ov[2], ov[3]);
  }
  __syncthreads();

  const int S = min(s_cnt, 96);
  const int nc = min(s_nc, 128);
  const int needC = K_ - S;

  // ---- round-1-arithmetic recompute of candidates (one thread each):
  // sequential ascending-k fp32 fmaf chain, then +be (separate add).
  // (matches the empirically-passing fp32 np ref ordering — do not
  //  "improve" to fp64/reordered: rounds 3/4 failed that way.)
  if (tid < nc) {
    const int h = cand[tid];
    const float* __restrict__ wrow = &We[(size_t)h * D_];
    float acc = 0.f;
    for (int kk = 0; kk < D_; ++kk) acc = fmaf(xsh[kk], wrow[kk], acc);
    zex[tid] = acc + be[h];
  }
  __syncthreads();

  // ---- select needC among candidates (idx tie-break) ----
  for (int c = tid; c < nc; c += 256) {
    const float zc = zex[c];
    const int hc = cand[c];
    int rank = 0;
    for (int q = 0; q < nc; ++q) {
      float zq = zex[q];
      rank += ((zq > zc) || (zq == zc && cand[q] < hc)) ? 1 : 0;
    }
    if (rank < needC) {
      zrow[hc] = zc;
      int p = atomicAdd(&s_cnt, 1);
      if (p < 96) { svals[p] = zc; sidx[p] = hc; }
    }
  }
  __syncthreads();

  // ---- decode: recon[b,:] = bd + sum v_k * We[h_k,:] ----
  const int n = min(s_cnt, 96);
  const int d0 = tid * 4;
  float4 a = *(const float4*)&bd[d0];
  for (int kk = 0; kk < n; ++kk) {
    const float v = svals[kk];
    const float4 w = *(const float4*)&We[(size_t)sidx[kk] * D_ + d0];
    a.x = fmaf(v, w.x, a.x);
    a.y = fmaf(v, w.y, a.y);
    a.z = fmaf(v, w.z, a.z);
    a.w = fmaf(v, w.w, a.w);
  }
  *(float4*)&recon[(size_t)bid * D_ + d0] = a;
}

// =====================================================================
// Fallback fp32 encoder (only if ws too small) — round-1 validated.
// =====================================================================
__global__ __launch_bounds__(256) void encoder_kernel(
    const float* __restrict__ x, const float* __restrict__ We,
    const float* __restrict__ be, float* __restrict__ z)
{
  __shared__ float Asf[16][132];
  __shared__ float Bsf[16][132];
  const int tid = threadIdx.x;
  const int bm = blockIdx.y * 128;
  const int bn = blockIdx.x * 128;
  const int tx = tid & 15;
  const int ty = tid >> 4;
  const int lr = tid >> 2;
  const int lc = (tid & 3) << 2;
  const float* pA0 = x + (size_t)(bm + lr) * D_ + lc;
  const float* pA1 = x + (size_t)(bm + lr + 64) * D_ + lc;
  const float* pB0 = We + (size_t)(bn + lr) * D_ + lc;
  const float* pB1 = We + (size_t)(bn + lr + 64) * D_ + lc;
  float acc[8][8];
#pragma unroll
  for (int i = 0; i < 8; ++i)
#pragma unroll
    for (int j = 0; j < 8; ++j) acc[i][j] = 0.f;
  float4 a0 = *(const float4*)(pA0);
  float4 a1 = *(const float4*)(pA1);
  float4 b0 = *(const float4*)(pB0);
  float4 b1 = *(const float4*)(pB1);
  for (int k0 = 0; k0 < D_; k0 += 16) {
    __syncthreads();
    Asf[lc + 0][lr] = a0.x; Asf[lc + 1][lr] = a0.y; Asf[lc + 2][lr] = a0.z; Asf[lc + 3][lr] = a0.w;
    Asf[lc + 0][lr + 64] = a1.x; Asf[lc + 1][lr + 64] = a1.y; Asf[lc + 2][lr + 64] = a1.z; Asf[lc + 3][lr + 64] = a1.w;
    Bsf[lc + 0][lr] = b0.x; Bsf[lc + 1][lr] = b0.y; Bsf[lc + 2][lr] = b0.z; Bsf[lc + 3][lr] = b0.w;
    Bsf[lc + 0][lr + 64] = b1.x; Bsf[lc + 1][lr + 64] = b1.y; Bsf[lc + 2][lr + 64] = b1.z; Bsf[lc + 3][lr + 64] = b1.w;
    __syncthreads();
    if (k0 + 16 < D_) {
      a0 = *(const float4*)(pA0 + k0 + 16);
      a1 = *(const float4*)(pA1 + k0 + 16);
      b0 = *(const float4*)(pB0 + k0 + 16);
      b1 = *(const float4*)(pB1 + k0 + 16);
    }
#pragma unroll
    for (int k = 0; k < 16; ++k) {
      float a[8], b[8];
      *(float4*)&a[0] = *(const float4*)&Asf[k][ty * 4];
      *(float4*)&a[4] = *(const float4*)&Asf[k][64 + ty * 4];
      *(float4*)&b[0] = *(const float4*)&Bsf[k][tx * 4];
      *(float4*)&b[4] = *(const float4*)&Bsf[k][64 + tx * 4];
#pragma unroll
      for (int i = 0; i < 8; ++i)
#pragma unroll
        for (int j = 0; j < 8; ++j) acc[i][j] = fmaf(a[i], b[j], acc[i][j]);
    }
  }
  float bev[8];
#pragma unroll
  for (int j = 0; j < 8; ++j) {
    int cn = (j < 4) ? (bn + tx * 4 + j) : (bn + 64 + tx * 4 + (j - 4));
    bev[j] = be[cn];
  }
#pragma unroll
  for (int i = 0; i < 8; ++i) {
    int rm = (i < 4) ? (bm + ty * 4 + i) : (bm + 64 + ty * 4 + (i - 4));
    float4 v0 = make_float4(acc[i][0] + bev[0], acc[i][1] + bev[1],
                            acc[i][2] + bev[2], acc[i][3] + bev[3]);
    float4 v1 = make_float4(acc[i][4] + bev[4], acc[i][5] + bev[5],
                            acc[i][6] + bev[6], acc[i][7] + bev[7]);
    *(float4*)&z[(size_t)rm * H_ + bn + tx * 4] = v0;
    *(float4*)&z[(size_t)rm * H_ + bn + 64 + tx * 4] = v1;
  }
}

extern "C" void kernel_launch(void* const* d_in, const int* in_sizes, int n_in,
                              void* d_out, int out_size, void* d_ws, size_t ws_size,
                              hipStream_t stream) {
  const float* x  = (const float*)d_in[0];
  const float* We = (const float*)d_in[1];
  const float* be = (const float*)d_in[2];
  const float* bd = (const float*)d_in[4];   // d_in[3]=Wd==We.T unused; gather We rows

  float* recon = (float*)d_out;                     // (B, D)
  float* zsp   = (float*)d_out + (size_t)B_ * D_;   // (B, H): z -> z_sparse in place

  const size_t need_ws = 2ull * 8192 * KPHYS * sizeof(unsigned short);  // 67.1 MB
  if (ws_size >= need_ws) {
    unsigned short* Ac = (unsigned short*)d_ws;
    unsigned short* Bc = Ac + (size_t)8192 * KPHYS;
    split_bf16_kernel<<<8192, 256, 0, stream>>>(x, Ac);
    split_bf16_kernel<<<8192, 256, 0, stream>>>(We, Bc);
    enc_mfma_kernel<<<dim3(64, 64), 256, 0, stream>>>(Ac, Bc, be, zsp);
  } else {
    encoder_kernel<<<dim3(64, 64), 256, 0, stream>>>(x, We, be, zsp);
  }
  topk_decode_kernel<<<B_, 256, 0, stream>>>(zsp, x, We, be, bd, recon);
}

// Round 7
// 999.063 us; speedup vs baseline: 2.4605x; 1.2654x over previous
//
#include <hip/hip_runtime.h>

#define B_ 8192
#define D_ 1024
#define H_ 8192
#define K_ 64
#define KPH 1024     // hi-plane bf16 columns
#define DELTA 1.5e-2f  // band half-width >= 2*max|z - z_hi| (~1.06e-2) w/ margin

typedef __attribute__((ext_vector_type(8))) short bf16x8;
typedef __attribute__((ext_vector_type(4))) float f32x4;

// ---- monotonic fp32 <-> u32 key (descending top-k == largest keys) ----
__device__ __forceinline__ unsigned f2key(float f) {
  unsigned u = __float_as_uint(f);
  return (u & 0x80000000u) ? ~u : (u | 0x80000000u);
}
__device__ __forceinline__ float key2f(unsigned k) {
  return (k & 0x80000000u) ? __uint_as_float(k ^ 0x80000000u)
                           : __uint_as_float(~k);
}

__device__ __forceinline__ unsigned short f32_to_bf16_rne(float f) {
  unsigned u = __float_as_uint(f);
  unsigned r = (u + 0x7FFFu + ((u >> 16) & 1u)) >> 16;
  return (unsigned short)r;
}
__device__ __forceinline__ float bf16_to_f32(unsigned short h) {
  return __uint_as_float(((unsigned)h) << 16);
}

__device__ __forceinline__ void gload_lds16(const void* g, void* l) {
  __builtin_amdgcn_global_load_lds(
      (const __attribute__((address_space(1))) unsigned int*)g,
      (__attribute__((address_space(3))) unsigned int*)l, 16, 0, 0);
}

// =====================================================================
// Split fp32 (R x 1024) -> bf16 hi plane (R x 1024)
// =====================================================================
__global__ __launch_bounds__(256) void split_hi_kernel(
    const float* __restrict__ src, unsigned short* __restrict__ dst)
{
  const int i = blockIdx.x * 256 + threadIdx.x;   // float4 index
  float4 v = *(const float4*)&src[(size_t)i * 4];
  ushort4 hi;
  hi.x = f32_to_bf16_rne(v.x);
  hi.y = f32_to_bf16_rne(v.y);
  hi.z = f32_to_bf16_rne(v.z);
  hi.w = f32_to_bf16_rne(v.w);
  *(ushort4*)&dst[(size_t)i * 4] = hi;
}

// =====================================================================
// Encoder GEMM (approx): z~[m][n] = sum_k xhi[m][k]*Whi[n][k] + be[n]
// 128x128 tile, BK=64, 4 waves, 16x16x32 bf16 MFMA, global_load_lds.
// Bank-conflict fix (rule #21 both-sides): linear LDS dest, pre-swizzled
// global source col, same XOR involution on fragment reads (round-6 ✓).
// =====================================================================
__global__ __launch_bounds__(256) void enc_mfma_kernel(
    const unsigned short* __restrict__ Ac,  // (B_, 1024) bf16 hi
    const unsigned short* __restrict__ Bc,  // (H_, 1024) bf16 hi
    const float* __restrict__ be, float* __restrict__ z)
{
  __shared__ unsigned short As[128 * 64];  // [row][64], row-major, linear
  __shared__ unsigned short Bs[128 * 64];

  const int tid = threadIdx.x;
  const int lane = tid & 63;
  const int wave = tid >> 6;
  const int wm = wave >> 1, wn = wave & 1;
  const int bm = blockIdx.y * 128;
  const int bn = blockIdx.x * 128;

  const int srow = lane >> 3;                            // 0..7 within chunk
  const int scol = (((lane & 7) ^ (lane >> 3)) << 3);    // SWIZZLED src col
  const unsigned short* pA[4];
  const unsigned short* pB[4];
  unsigned short* lA[4];
  unsigned short* lB[4];
#pragma unroll
  for (int it = 0; it < 4; ++it) {
    const int row = wave * 32 + it * 8 + srow;
    pA[it] = Ac + (size_t)(bm + row) * KPH + scol;
    pB[it] = Bc + (size_t)(bn + row) * KPH + scol;
    lA[it] = &As[(wave * 4 + it) * 512];
    lB[it] = &Bs[(wave * 4 + it) * 512];
  }

  f32x4 acc[4][4];
#pragma unroll
  for (int mi = 0; mi < 4; ++mi)
#pragma unroll
    for (int ni = 0; ni < 4; ++ni) acc[mi][ni] = (f32x4){0.f, 0.f, 0.f, 0.f};

  const int mrow = wm * 64 + (lane & 15);
  const int nrow = wn * 64 + (lane & 15);
  const int rsw = (lane & 7) << 4;          // read-side XOR field (bytes)
  const int cgrp = (lane >> 4) << 4;        // col-group byte offset

  for (int s = 0; s < 16; ++s) {
    const int kk0 = s * 64;
#pragma unroll
    for (int it = 0; it < 4; ++it) gload_lds16(pA[it] + kk0, lA[it]);
#pragma unroll
    for (int it = 0; it < 4; ++it) gload_lds16(pB[it] + kk0, lB[it]);
    __syncthreads();

#pragma unroll
    for (int kk = 0; kk < 2; ++kk) {
      const int ko = ((kk * 64 + cgrp) ^ rsw) >> 1;   // swizzled elem offset
      bf16x8 af[4], bfr[4];
#pragma unroll
      for (int mi = 0; mi < 4; ++mi)
        af[mi] = *(const bf16x8*)&As[(mrow + mi * 16) * 64 + ko];
#pragma unroll
      for (int ni = 0; ni < 4; ++ni)
        bfr[ni] = *(const bf16x8*)&Bs[(nrow + ni * 16) * 64 + ko];
#pragma unroll
      for (int mi = 0; mi < 4; ++mi)
#pragma unroll
        for (int ni = 0; ni < 4; ++ni)
          acc[mi][ni] = __builtin_amdgcn_mfma_f32_16x16x32_bf16(
              af[mi], bfr[ni], acc[mi][ni], 0, 0, 0);
    }
    __syncthreads();
  }

  float bev[4];
#pragma unroll
  for (int ni = 0; ni < 4; ++ni) bev[ni] = be[bn + wn * 64 + ni * 16 + (lane & 15)];
#pragma unroll
  for (int mi = 0; mi < 4; ++mi) {
#pragma unroll
    for (int r = 0; r < 4; ++r) {
      const int row = bm + wm * 64 + mi * 16 + (lane >> 4) * 4 + r;
      float* zr = &z[(size_t)row * H_ + bn + wn * 64 + (lane & 15)];
#pragma unroll
      for (int ni = 0; ni < 4; ++ni) zr[ni * 16] = acc[mi][ni][r] + bev[ni];
    }
  }
}

// =====================================================================
// Top-K (kernel A): bisection on register keys, classify, round-1
// fp32-chain fixup of boundary candidates, write z_sparse row + compact
// (val,idx) list for the decode kernel.
// =====================================================================
__global__ __launch_bounds__(256) void topk_kernel(
    float* __restrict__ zsp, const float* __restrict__ x,
    const float* __restrict__ We, const float* __restrict__ be,
    float* __restrict__ vals_g, int* __restrict__ idx_g)
{
  __shared__ float xsh[D_];         // 4 KB: x row for candidate recompute
  __shared__ int scnt[2][4];        // parity-buffered wave sums
  __shared__ int s_cnt;             // selected count (exactly 64 at end)
  __shared__ int s_nc;              // candidate count
  __shared__ int cand[128];
  __shared__ float zex[128];

  const int tid = threadIdx.x;
  const int wv = tid >> 6;
  const int bid = blockIdx.x;
  float* __restrict__ zrow = zsp + (size_t)bid * H_;
  float* __restrict__ vrow = vals_g + (size_t)bid * K_;
  int*   __restrict__ irow = idx_g + (size_t)bid * K_;

  // load 32 keys/thread into registers (coalesced float4)
  unsigned k[32];
#pragma unroll
  for (int t = 0; t < 8; ++t) {
    const int i4 = tid + t * 256;
    float4 v = *(const float4*)&zrow[i4 * 4];
    k[t * 4 + 0] = f2key(v.x);
    k[t * 4 + 1] = f2key(v.y);
    k[t * 4 + 2] = f2key(v.z);
    k[t * 4 + 3] = f2key(v.w);
  }
  for (int i = tid; i < D_; i += 256) xsh[i] = x[(size_t)bid * D_ + i];
  if (tid == 0) { s_cnt = 0; s_nc = 0; }

  // ---- bisection for the exact 64th-largest key ----
  unsigned lo = 0u, hi = 0xFFFFFFFFu;
  int par = 0;
  while (hi - lo > 1u) {
    const unsigned mid = lo + ((hi - lo) >> 1);
    int c = 0;
#pragma unroll
    for (int t = 0; t < 32; ++t) c += (k[t] >= mid) ? 1 : 0;
#pragma unroll
    for (int off = 32; off > 0; off >>= 1) c += __shfl_down(c, off);
    if ((tid & 63) == 0) scnt[par][wv] = c;
    __syncthreads();
    const int tot = scnt[par][0] + scnt[par][1] + scnt[par][2] + scnt[par][3];
    if (tot >= K_) lo = mid; else hi = mid;
    par ^= 1;
  }

  const float vthr = key2f(lo);
  const unsigned hiKey = f2key(vthr + DELTA);
  const unsigned loKey = f2key(vthr - DELTA);

  // ---- classify + write zeros/safe values, collect candidates ----
#pragma unroll
  for (int t = 0; t < 8; ++t) {
    const int base = (tid + t * 256) * 4;
    float ov[4];
#pragma unroll
    for (int j = 0; j < 4; ++j) {
      const unsigned key = k[t * 4 + j];
      float v = 0.f;
      if (key > hiKey) {                 // safely in top-64
        v = key2f(key);
        int p = atomicAdd(&s_cnt, 1);
        if (p < K_) { vrow[p] = v; irow[p] = base + j; }
      } else if (key >= loKey) {         // boundary candidate
        int p = atomicAdd(&s_nc, 1);
        if (p < 128) cand[p] = base + j;
      }
      ov[j] = v;
    }
    *(float4*)&zrow[base] = make_float4(ov[0], ov[1], ov[2], ov[3]);
  }
  __syncthreads();

  const int S = min(s_cnt, K_);
  const int nc = min(s_nc, 128);
  const int needC = K_ - S;

  // ---- round-1-arithmetic recompute of candidates (one thread each):
  // sequential ascending-k fp32 fmaf chain, then +be (separate add).
  // Matches the fp32-ordered np ref; do NOT "improve" to fp64 (r3/r4 failed).
  if (tid < nc) {
    const int h = cand[tid];
    const float* __restrict__ wrow = &We[(size_t)h * D_];
    float acc = 0.f;
    for (int kk = 0; kk < D_; ++kk) acc = fmaf(xsh[kk], wrow[kk], acc);
    zex[tid] = acc + be[h];
  }
  __syncthreads();

  // ---- select needC among candidates (idx tie-break) ----
  for (int c = tid; c < nc; c += 256) {
    const float zc = zex[c];
    const int hc = cand[c];
    int rank = 0;
    for (int q = 0; q < nc; ++q) {
      float zq = zex[q];
      rank += ((zq > zc) || (zq == zc && cand[q] < hc)) ? 1 : 0;
    }
    if (rank < needC) {
      zrow[hc] = zc;
      int p = atomicAdd(&s_cnt, 1);
      if (p < K_) { vrow[p] = zc; irow[p] = hc; }
    }
  }
}

// =====================================================================
// Decode (kernel B): recon[b,:] = bd + sum_k v_k * We_hi[h_k,:]
// Gathers bf16-hi We rows (16 MB, L2/L3-resident; no big stream evicting).
// =====================================================================
__global__ __launch_bounds__(256) void decode_kernel(
    const float* __restrict__ vals_g, const int* __restrict__ idx_g,
    const unsigned short* __restrict__ Bc,   // (H_, 1024) bf16 hi
    const float* __restrict__ bd, float* __restrict__ recon)
{
  __shared__ float sv[K_];
  __shared__ int si[K_];
  const int tid = threadIdx.x;
  const int bid = blockIdx.x;
  if (tid < K_) {
    sv[tid] = vals_g[(size_t)bid * K_ + tid];
    si[tid] = idx_g[(size_t)bid * K_ + tid];
  }
  __syncthreads();
  const int d0 = tid * 4;
  float4 a = *(const float4*)&bd[d0];
#pragma unroll 4
  for (int kk = 0; kk < K_; ++kk) {
    const float v = sv[kk];
    ushort4 w = *(const ushort4*)&Bc[(size_t)si[kk] * KPH + d0];
    a.x = fmaf(v, bf16_to_f32(w.x), a.x);
    a.y = fmaf(v, bf16_to_f32(w.y), a.y);
    a.z = fmaf(v, bf16_to_f32(w.z), a.z);
    a.w = fmaf(v, bf16_to_f32(w.w), a.w);
  }
  *(float4*)&recon[(size_t)bid * D_ + d0] = a;
}

// =====================================================================
// Fallback path (ws too small): fp32 encoder + fused topk+decode (r6 ✓).
// =====================================================================
__global__ __launch_bounds__(256) void encoder_kernel(
    const float* __restrict__ x, const float* __restrict__ We,
    const float* __restrict__ be, float* __restrict__ z)
{
  __shared__ float Asf[16][132];
  __shared__ float Bsf[16][132];
  const int tid = threadIdx.x;
  const int bm = blockIdx.y * 128;
  const int bn = blockIdx.x * 128;
  const int tx = tid & 15;
  const int ty = tid >> 4;
  const int lr = tid >> 2;
  const int lc = (tid & 3) << 2;
  const float* pA0 = x + (size_t)(bm + lr) * D_ + lc;
  const float* pA1 = x + (size_t)(bm + lr + 64) * D_ + lc;
  const float* pB0 = We + (size_t)(bn + lr) * D_ + lc;
  const float* pB1 = We + (size_t)(bn + lr + 64) * D_ + lc;
  float acc[8][8];
#pragma unroll
  for (int i = 0; i < 8; ++i)
#pragma unroll
    for (int j = 0; j < 8; ++j) acc[i][j] = 0.f;
  float4 a0 = *(const float4*)(pA0);
  float4 a1 = *(const float4*)(pA1);
  float4 b0 = *(const float4*)(pB0);
  float4 b1 = *(const float4*)(pB1);
  for (int k0 = 0; k0 < D_; k0 += 16) {
    __syncthreads();
    Asf[lc + 0][lr] = a0.x; Asf[lc + 1][lr] = a0.y; Asf[lc + 2][lr] = a0.z; Asf[lc + 3][lr] = a0.w;
    Asf[lc + 0][lr + 64] = a1.x; Asf[lc + 1][lr + 64] = a1.y; Asf[lc + 2][lr + 64] = a1.z; Asf[lc + 3][lr + 64] = a1.w;
    Bsf[lc + 0][lr] = b0.x; Bsf[lc + 1][lr] = b0.y; Bsf[lc + 2][lr] = b0.z; Bsf[lc + 3][lr] = b0.w;
    Bsf[lc + 0][lr + 64] = b1.x; Bsf[lc + 1][lr + 64] = b1.y; Bsf[lc + 2][lr + 64] = b1.z; Bsf[lc + 3][lr + 64] = b1.w;
    __syncthreads();
    if (k0 + 16 < D_) {
      a0 = *(const float4*)(pA0 + k0 + 16);
      a1 = *(const float4*)(pA1 + k0 + 16);
      b0 = *(const float4*)(pB0 + k0 + 16);
      b1 = *(const float4*)(pB1 + k0 + 16);
    }
#pragma unroll
    for (int k = 0; k < 16; ++k) {
      float a[8], b[8];
      *(float4*)&a[0] = *(const float4*)&Asf[k][ty * 4];
      *(float4*)&a[4] = *(const float4*)&Asf[k][64 + ty * 4];
      *(float4*)&b[0] = *(const float4*)&Bsf[k][tx * 4];
      *(float4*)&b[4] = *(const float4*)&Bsf[k][64 + tx * 4];
#pragma unroll
      for (int i = 0; i < 8; ++i)
#pragma unroll
        for (int j = 0; j < 8; ++j) acc[i][j] = fmaf(a[i], b[j], acc[i][j]);
    }
  }
  float bev[8];
#pragma unroll
  for (int j = 0; j < 8; ++j) {
    int cn = (j < 4) ? (bn + tx * 4 + j) : (bn + 64 + tx * 4 + (j - 4));
    bev[j] = be[cn];
  }
#pragma unroll
  for (int i = 0; i < 8; ++i) {
    int rm = (i < 4) ? (bm + ty * 4 + i) : (bm + 64 + ty * 4 + (i - 4));
    float4 v0 = make_float4(acc[i][0] + bev[0], acc[i][1] + bev[1],
                            acc[i][2] + bev[2], acc[i][3] + bev[3]);
    float4 v1 = make_float4(acc[i][4] + bev[4], acc[i][5] + bev[5],
                            acc[i][6] + bev[6], acc[i][7] + bev[7]);
    *(float4*)&z[(size_t)rm * H_ + bn + tx * 4] = v0;
    *(float4*)&z[(size_t)rm * H_ + bn + 64 + tx * 4] = v1;
  }
}

__global__ __launch_bounds__(256) void topk_decode_fb_kernel(
    float* __restrict__ zsp, const float* __restrict__ x,
    const float* __restrict__ We, const float* __restrict__ be,
    const float* __restrict__ bd, float* __restrict__ recon)
{
  __shared__ float xsh[D_];
  __shared__ int scnt[2][4];
  __shared__ int s_cnt;
  __shared__ int s_nc;
  __shared__ int cand[128];
  __shared__ float zex[128];
  __shared__ float svals[96];
  __shared__ int sidx[96];

  const int tid = threadIdx.x;
  const int wv = tid >> 6;
  const int bid = blockIdx.x;
  float* __restrict__ zrow = zsp + (size_t)bid * H_;

  unsigned k[32];
#pragma unroll
  for (int t = 0; t < 8; ++t) {
    const int i4 = tid + t * 256;
    float4 v = *(const float4*)&zrow[i4 * 4];
    k[t * 4 + 0] = f2key(v.x);
    k[t * 4 + 1] = f2key(v.y);
    k[t * 4 + 2] = f2key(v.z);
    k[t * 4 + 3] = f2key(v.w);
  }
  for (int i = tid; i < D_; i += 256) xsh[i] = x[(size_t)bid * D_ + i];
  if (tid == 0) { s_cnt = 0; s_nc = 0; }

  unsigned lo = 0u, hi = 0xFFFFFFFFu;
  int par = 0;
  while (hi - lo > 1u) {
    const unsigned mid = lo + ((hi - lo) >> 1);
    int c = 0;
#pragma unroll
    for (int t = 0; t < 32; ++t) c += (k[t] >= mid) ? 1 : 0;
#pragma unroll
    for (int off = 32; off > 0; off >>= 1) c += __shfl_down(c, off);
    if ((tid & 63) == 0) scnt[par][wv] = c;
    __syncthreads();
    const int tot = scnt[par][0] + scnt[par][1] + scnt[par][2] + scnt[par][3];
    if (tot >= K_) lo = mid; else hi = mid;
    par ^= 1;
  }

  const float vthr = key2f(lo);
  const unsigned hiKey = f2key(vthr + DELTA);
  const unsigned loKey = f2key(vthr - DELTA);

#pragma unroll
  for (int t = 0; t < 8; ++t) {
    const int base = (tid + t * 256) * 4;
    float ov[4];
#pragma unroll
    for (int j = 0; j < 4; ++j) {
      const unsigned key = k[t * 4 + j];
      float v = 0.f;
      if (key > hiKey) {
        v = key2f(key);
        int p = atomicAdd(&s_cnt, 1);
        if (p < 96) { svals[p] = v; sidx[p] = base + j; }
      } else if (key >= loKey) {
        int p = atomicAdd(&s_nc, 1);
        if (p < 128) cand[p] = base + j;
      }
      ov[j] = v;
    }
    *(float4*)&zrow[base] = make_float4(ov[0], ov[1], ov[2], ov[3]);
  }
  __syncthreads();

  const int S = min(s_cnt, 96);
  const int nc = min(s_nc, 128);
  const int needC = K_ - S;

  if (tid < nc) {
    const int h = cand[tid];
    const float* __restrict__ wrow = &We[(size_t)h * D_];
    float acc = 0.f;
    for (int kk = 0; kk < D_; ++kk) acc = fmaf(xsh[kk], wrow[kk], acc);
    zex[tid] = acc + be[h];
  }
  __syncthreads();

  for (int c = tid; c < nc; c += 256) {
    const float zc = zex[c];
    const int hc = cand[c];
    int rank = 0;
    for (int q = 0; q < nc; ++q) {
      float zq = zex[q];
      rank += ((zq > zc) || (zq == zc && cand[q] < hc)) ? 1 : 0;
    }
    if (rank < needC) {
      zrow[hc] = zc;
      int p = atomicAdd(&s_cnt, 1);
      if (p < 96) { svals[p] = zc; sidx[p] = hc; }
    }
  }
  __syncthreads();

  const int n = min(s_cnt, 96);
  const int d0 = tid * 4;
  float4 a = *(const float4*)&bd[d0];
  for (int kk = 0; kk < n; ++kk) {
    const float v = svals[kk];
    const float4 w = *(const float4*)&We[(size_t)sidx[kk] * D_ + d0];
    a.x = fmaf(v, w.x, a.x);
    a.y = fmaf(v, w.y, a.y);
    a.z = fmaf(v, w.z, a.z);
    a.w = fmaf(v, w.w, a.w);
  }
  *(float4*)&recon[(size_t)bid * D_ + d0] = a;
}

extern "C" void kernel_launch(void* const* d_in, const int* in_sizes, int n_in,
                              void* d_out, int out_size, void* d_ws, size_t ws_size,
                              hipStream_t stream) {
  const float* x  = (const float*)d_in[0];
  const float* We = (const float*)d_in[1];
  const float* be = (const float*)d_in[2];
  const float* bd = (const float*)d_in[4];   // d_in[3]=Wd==We.T unused; gather We rows

  float* recon = (float*)d_out;                     // (B, D)
  float* zsp   = (float*)d_out + (size_t)B_ * D_;   // (B, H): z~ -> z_sparse in place

  const size_t szA = (size_t)B_ * KPH * sizeof(unsigned short);  // 16.8 MB
  const size_t szB = (size_t)H_ * KPH * sizeof(unsigned short);  // 16.8 MB
  const size_t szV = (size_t)B_ * K_ * sizeof(float);            // 2 MB
  const size_t szI = (size_t)B_ * K_ * sizeof(int);              // 2 MB
  const size_t need_ws = szA + szB + szV + szI;

  if (ws_size >= need_ws) {
    unsigned short* Ac = (unsigned short*)d_ws;
    unsigned short* Bc = (unsigned short*)((char*)d_ws + szA);
    float* vals_g = (float*)((char*)d_ws + szA + szB);
    int* idx_g = (int*)((char*)d_ws + szA + szB + szV);
    split_hi_kernel<<<(B_ * D_ / 4 + 255) / 256, 256, 0, stream>>>(x, Ac);
    split_hi_kernel<<<(H_ * D_ / 4 + 255) / 256, 256, 0, stream>>>(We, Bc);
    enc_mfma_kernel<<<dim3(64, 64), 256, 0, stream>>>(Ac, Bc, be, zsp);
    topk_kernel<<<B_, 256, 0, stream>>>(zsp, x, We, be, vals_g, idx_g);
    decode_kernel<<<B_, 256, 0, stream>>>(vals_g, idx_g, Bc, bd, recon);
  } else {
    encoder_kernel<<<dim3(64, 64), 256, 0, stream>>>(x, We, be, zsp);
    topk_decode_fb_kernel<<<B_, 256, 0, stream>>>(zsp, x, We, be, bd, recon);
  }
}